// Round 6
// baseline (173.765 us; speedup 1.0000x reference)
//
#include <hip/hip_runtime.h>
#include <hip/hip_bf16.h>

#define B_  2
#define S_  2048
#define D_  1024
#define H_  16
#define DH_ 64

typedef __attribute__((ext_vector_type(8))) short bf16x8;
typedef __attribute__((ext_vector_type(4))) float f32x4;

__device__ __forceinline__ short f2bf(float f) {
  unsigned int u; __builtin_memcpy(&u, &f, 4);
  u = (u + 0x7FFFu + ((u >> 16) & 1u)) >> 16;
  return (short)u;
}
// packed f32x2 -> bf16x2 (RNE), lo = first arg  [T12 recipe, no builtin on gfx950]
__device__ __forceinline__ unsigned cvtpk(float a, float b) {
  unsigned r;
  asm("v_cvt_pk_bf16_f32 %0, %1, %2" : "=v"(r) : "v"(a), "v"(b));
  return r;
}

#define GLOAD_LDS16(gp, lp) \
  __builtin_amdgcn_global_load_lds((const __attribute__((address_space(1))) void*)(gp), \
                                   (__attribute__((address_space(3))) void*)(lp), 16, 0, 0)

#define MFMA16(a, b, c) __builtin_amdgcn_mfma_f32_16x16x32_bf16(a, b, c, 0, 0, 0)

union U8 { unsigned u[4]; bf16x8 v; };

// ---------------- f32 -> bf16 convert (x) ----------------
__global__ __launch_bounds__(256) void k_cvt(const float* __restrict__ in,
                                             short* __restrict__ out, int n4) {
  int i = blockIdx.x * 256 + threadIdx.x;
  if (i >= n4) return;
  float4 v = ((const float4*)in)[i];
  short4 o; o.x = f2bf(v.x); o.y = f2bf(v.y); o.z = f2bf(v.z); o.w = f2bf(v.w);
  *(short4*)(out + (size_t)i * 4) = o;
}

// ---------------- W (f32 [K][N]) -> Wt (bf16 [N][K]) ----------------
__global__ __launch_bounds__(256) void k_transpose(const float* __restrict__ W,
                                                   short* __restrict__ Wt) {
  __shared__ float tile[32][33];
  int tx = threadIdx.x, ty = threadIdx.y;
  int bx = blockIdx.x * 32, by = blockIdx.y * 32;
  #pragma unroll
  for (int i = 0; i < 32; i += 8)
    tile[ty + i][tx] = W[(size_t)(by + ty + i) * D_ + bx + tx];
  __syncthreads();
  #pragma unroll
  for (int i = 0; i < 32; i += 8)
    Wt[(size_t)(bx + ty + i) * D_ + by + tx] = f2bf(tile[tx][ty + i]);
}

// ---------------- RoPE cos/sin table ----------------
__global__ __launch_bounds__(256) void k_rope_table(float* __restrict__ cosT,
                                                    float* __restrict__ sinT) {
  int i = blockIdx.x * 256 + threadIdx.x;  // S_*32 entries
  int s = i >> 5, d = i & 31;
  float invf = exp2f(-(float)d * (13.287712379549449f / 32.0f)); // 10000^(-d/32)
  float ang = (float)s * invf;
  cosT[i] = cosf(ang);
  sinT[i] = sinf(ang);
}

// ---------------- fused Q,K GEMM + bias + RoPE epilogue ----------------
// C[4096,2048] = xb * [wqT;wkT]^T; RoPE in-register; Q scaled by (1/8)*log2e.
__global__ __launch_bounds__(256) void k_gemm_qkv(const short* __restrict__ A,
                                                  const short* __restrict__ Bt,
                                                  const float* __restrict__ bq,
                                                  const float* __restrict__ bk,
                                                  const float* __restrict__ cosT,
                                                  const float* __restrict__ sinT,
                                                  short* __restrict__ qb,
                                                  short* __restrict__ kb) {
  const int K = 1024;
  __shared__ __align__(16) short lA[128 * 32];
  __shared__ __align__(16) short lB[128 * 32];
  const int tid = threadIdx.x;
  const int wid = tid >> 6, lane = tid & 63;
  const int brow = blockIdx.y * 128, bcol = blockIdx.x * 128;
  const int wr = wid >> 1, wc = wid & 1;
  const int g = lane >> 4, c15 = lane & 15;
  const int sr = lane >> 2, scol = (lane & 3) * 8;
  f32x4 acc[4][4] = {};

  for (int kt = 0; kt < K; kt += 32) {
    __syncthreads();
    #pragma unroll
    for (int ch = 0; ch < 2; ++ch) {
      const short* ga = A + (size_t)(brow + ch * 64 + wid * 16 + sr) * K + kt + scol;
      const short* gb = Bt + (size_t)(bcol + ch * 64 + wid * 16 + sr) * K + kt + scol;
      GLOAD_LDS16(ga, &lA[(ch * 64 + wid * 16) * 32]);
      GLOAD_LDS16(gb, &lB[(ch * 64 + wid * 16) * 32]);
    }
    __syncthreads();
    bf16x8 af[4], bfr[4];
    #pragma unroll
    for (int mi = 0; mi < 4; ++mi)
      af[mi] = *(const bf16x8*)&lA[(wr * 64 + mi * 16 + c15) * 32 + g * 8];
    #pragma unroll
    for (int ni = 0; ni < 4; ++ni)
      bfr[ni] = *(const bf16x8*)&lB[(wc * 64 + ni * 16 + c15) * 32 + g * 8];
    #pragma unroll
    for (int mi = 0; mi < 4; ++mi)
      #pragma unroll
      for (int ni = 0; ni < 4; ++ni)
        acc[mi][ni] = MFMA16(af[mi], bfr[ni], acc[mi][ni]);
  }

  // epilogue: segment select (block-uniform), bias, alpha, rope pair rotation
  const int seg = bcol >> 10;                       // 0=q 1=k
  const float* bp = (seg == 0) ? bq : bk;
  short* dst = (seg == 0) ? qb : kb;
  const float alpha = (seg == 0) ? 0.18033688f : 1.0f;  // (1/8)*log2(e)
  #pragma unroll
  for (int mi = 0; mi < 4; ++mi) {
    #pragma unroll
    for (int ni = 0; ni < 2; ++ni) {
      int col  = bcol + wc * 64 + ni * 16 + c15;
      int lcol = col & 1023;
      int d    = col & 63;                          // 0..31 (ni<2)
      float b1 = bp[lcol], b2 = bp[lcol + 32];
      #pragma unroll
      for (int r = 0; r < 4; ++r) {
        int row = brow + wr * 64 + mi * 16 + g * 4 + r;
        float x1 = (acc[mi][ni][r]     + b1) * alpha;
        float x2 = (acc[mi][ni + 2][r] + b2) * alpha;
        int s = row & (S_ - 1);
        float co = cosT[s * 32 + d], si = sinT[s * 32 + d];
        dst[(size_t)row * 1024 + lcol]      = f2bf(x1 * co - x2 * si);
        dst[(size_t)row * 1024 + lcol + 32] = f2bf(x1 * si + x2 * co);
      }
    }
  }
}

// ---------------- V^T GEMM: vt[1024,4096] = wvT * xb^T + bv (bias per ROW) ----------------
// vt[m][n] = sum_k wvT[m][k]*xb[n][k] = v[n][m]; layout vt[(h*64+d)][b*2048+s].
__global__ __launch_bounds__(256) void k_gemm_vt(const short* __restrict__ A,
                                                 const short* __restrict__ Bt,
                                                 const float* __restrict__ bias,
                                                 short* __restrict__ out) {
  const int K = 1024, N = 4096;
  __shared__ __align__(16) short lA[128 * 32];
  __shared__ __align__(16) short lB[128 * 32];
  const int tid = threadIdx.x;
  const int wid = tid >> 6, lane = tid & 63;
  const int brow = blockIdx.y * 128, bcol = blockIdx.x * 128;
  const int wr = wid >> 1, wc = wid & 1;
  const int g = lane >> 4, c15 = lane & 15;
  const int sr = lane >> 2, scol = (lane & 3) * 8;
  f32x4 acc[4][4] = {};

  for (int kt = 0; kt < K; kt += 32) {
    __syncthreads();
    #pragma unroll
    for (int ch = 0; ch < 2; ++ch) {
      const short* ga = A + (size_t)(brow + ch * 64 + wid * 16 + sr) * K + kt + scol;
      const short* gb = Bt + (size_t)(bcol + ch * 64 + wid * 16 + sr) * K + kt + scol;
      GLOAD_LDS16(ga, &lA[(ch * 64 + wid * 16) * 32]);
      GLOAD_LDS16(gb, &lB[(ch * 64 + wid * 16) * 32]);
    }
    __syncthreads();
    bf16x8 af[4], bfr[4];
    #pragma unroll
    for (int mi = 0; mi < 4; ++mi)
      af[mi] = *(const bf16x8*)&lA[(wr * 64 + mi * 16 + c15) * 32 + g * 8];
    #pragma unroll
    for (int ni = 0; ni < 4; ++ni)
      bfr[ni] = *(const bf16x8*)&lB[(wc * 64 + ni * 16 + c15) * 32 + g * 8];
    #pragma unroll
    for (int mi = 0; mi < 4; ++mi)
      #pragma unroll
      for (int ni = 0; ni < 4; ++ni)
        acc[mi][ni] = MFMA16(af[mi], bfr[ni], acc[mi][ni]);
  }

  #pragma unroll
  for (int mi = 0; mi < 4; ++mi) {
    #pragma unroll
    for (int ni = 0; ni < 4; ++ni) {
      int col = bcol + wc * 64 + ni * 16 + c15;
      #pragma unroll
      for (int r = 0; r < 4; ++r) {
        int row = brow + wr * 64 + mi * 16 + g * 4 + r;
        out[(size_t)row * N + col] = f2bf(acc[mi][ni][r] + bias[row]);
      }
    }
  }
}

// ---------------- bf16 GEMM (Wo): C = A*Bt^T + bias(col), f32 out ----------------
__global__ __launch_bounds__(256) void k_gemm(const short* __restrict__ A,
                                              const short* __restrict__ Bt,
                                              const float* __restrict__ bias,
                                              float* __restrict__ out,
                                              int M, int N, int K) {
  __shared__ __align__(16) short lA[128 * 32];
  __shared__ __align__(16) short lB[128 * 32];
  const int tid = threadIdx.x;
  const int wid = tid >> 6, lane = tid & 63;
  const int brow = blockIdx.y * 128, bcol = blockIdx.x * 128;
  const int wr = wid >> 1, wc = wid & 1;
  const int g = lane >> 4, c15 = lane & 15;
  const int sr = lane >> 2, scol = (lane & 3) * 8;
  f32x4 acc[4][4] = {};

  for (int kt = 0; kt < K; kt += 32) {
    __syncthreads();
    #pragma unroll
    for (int ch = 0; ch < 2; ++ch) {
      const short* ga = A + (size_t)(brow + ch * 64 + wid * 16 + sr) * K + kt + scol;
      const short* gb = Bt + (size_t)(bcol + ch * 64 + wid * 16 + sr) * K + kt + scol;
      GLOAD_LDS16(ga, &lA[(ch * 64 + wid * 16) * 32]);
      GLOAD_LDS16(gb, &lB[(ch * 64 + wid * 16) * 32]);
    }
    __syncthreads();
    bf16x8 af[4], bfr[4];
    #pragma unroll
    for (int mi = 0; mi < 4; ++mi)
      af[mi] = *(const bf16x8*)&lA[(wr * 64 + mi * 16 + c15) * 32 + g * 8];
    #pragma unroll
    for (int ni = 0; ni < 4; ++ni)
      bfr[ni] = *(const bf16x8*)&lB[(wc * 64 + ni * 16 + c15) * 32 + g * 8];
    #pragma unroll
    for (int mi = 0; mi < 4; ++mi)
      #pragma unroll
      for (int ni = 0; ni < 4; ++ni)
        acc[mi][ni] = MFMA16(af[mi], bfr[ni], acc[mi][ni]);
  }

  #pragma unroll
  for (int mi = 0; mi < 4; ++mi) {
    #pragma unroll
    for (int ni = 0; ni < 4; ++ni) {
      int col = bcol + wc * 64 + ni * 16 + c15;
      float bv = bias[col];
      #pragma unroll
      for (int r = 0; r < 4; ++r) {
        int row = brow + wr * 64 + mi * 16 + g * 4 + r;
        out[(size_t)row * N + col] = acc[mi][ni][r] + bv;
      }
    }
  }
}

// ---------------- causal flash attention ----------------
// Swapped QK^T on 16x16x32 MFMA. grid 1024 = 32 q-tiles (big-first) x 32 bh;
// 4 waves, wave w owns q rows [qt*64+w*16, +16). KV tile 64.
// K: global_load_lds staged (swizzled, dbuf, 1-tile prefetch). V: B-frags read
// straight from global vt[d][s] (L2-resident, kv-contiguous b128) — no V LDS.
// Softmax in-register, exp2-direct (Q pre-scaled by (1/8)*log2e).
__global__ __launch_bounds__(256) void k_flash(const short* __restrict__ Qb,
                                               const short* __restrict__ Kb,
                                               const short* __restrict__ Vt,
                                               short* __restrict__ Ctx) {
  __shared__ __align__(16) short Kl[2][4096];  // K[kv][d] at kv*64 + ((d>>3)^(kv&7))*8 + (d&7)
  const int bid = blockIdx.x;
  const int qt  = (S_ / 64 - 1) - (bid >> 5);  // big q-tiles first
  const int bh  = bid & 31;
  const int b   = bh >> 4, h = bh & 15;
  const int tid = threadIdx.x, w = tid >> 6, lane = tid & 63;
  const int g   = lane >> 4, c15 = lane & 15;
  const int qg0 = qt * 64 + w * 16;
  const int qabs = qg0 + c15;

  // Q fragments (B-operand of swapped QK^T): lane holds Q[q=c15][g*8+j (+32)]
  const short* qp = Qb + ((size_t)(b * S_ + qabs)) * D_ + h * DH_ + g * 8;
  bf16x8 qf0 = *(const bf16x8*)qp;
  bf16x8 qf1 = *(const bf16x8*)(qp + 32);

  // V^T base for PV B-frags: row = h*64 + dblk*16 + c15, col = b*2048 + kv
  const short* vtq = Vt + ((size_t)(h * 64 + c15)) * 4096 + b * 2048 + g * 8;

  // K staging (DMA): wave w covers idx = w*128 + it*64 + lane, 16B each
  const short* kbase = Kb + (size_t)b * S_ * D_ + h * DH_;
  const int kidx0 = w * 128 + lane;
  const int kkv0 = kidx0 >> 3, kdb0 = (kidx0 & 7) ^ (kkv0 & 7);
  const int kidx1 = kidx0 + 64;
  const int kkv1 = kidx1 >> 3, kdb1 = (kidx1 & 7) ^ (kkv1 & 7);

  f32x4 o[4] = {};
  float m = -1e30f, l = 0.0f;
  const int nt = qt + 1;

  // prologue: stage K tile 0 into buf 0
  GLOAD_LDS16(kbase + (size_t)kkv0 * D_ + kdb0 * 8, &Kl[0][(w * 128) * 8]);
  GLOAD_LDS16(kbase + (size_t)kkv1 * D_ + kdb1 * 8, &Kl[0][(w * 128 + 64) * 8]);
  __syncthreads();

  for (int t = 0; t < nt; ++t) {
    const int kv0 = t * 64;
    // prefetch K tile t+1 via async DMA into the other buffer
    if (t + 1 < nt) {
      const short* kb2 = kbase + (size_t)(kv0 + 64) * D_;
      GLOAD_LDS16(kb2 + (size_t)kkv0 * D_ + kdb0 * 8, &Kl[(t + 1) & 1][(w * 128) * 8]);
      GLOAD_LDS16(kb2 + (size_t)kkv1 * D_ + kdb1 * 8, &Kl[(t + 1) & 1][(w * 128 + 64) * 8]);
    }
    // skip compute for tiles fully masked for this wave (staging+barrier still run)
    if (kv0 <= qg0 + 15) {
      // ---- S^T = K * Q^T : A-frag = K rows from LDS (swizzled) ----
      const short* ks = &Kl[t & 1][0];
      f32x4 s[4] = {};
      __builtin_amdgcn_s_setprio(1);
      #pragma unroll
      for (int n = 0; n < 4; ++n) {
        int krow = (n * 16 + c15) * 64;
        bf16x8 k0 = *(const bf16x8*)&ks[krow + ((g ^ (c15 & 7)) * 8)];
        bf16x8 k1 = *(const bf16x8*)&ks[krow + (((g + 4) ^ (c15 & 7)) * 8)];
        s[n] = MFMA16(k0, qf0, s[n]);
        s[n] = MFMA16(k1, qf1, s[n]);
      }
      __builtin_amdgcn_s_setprio(0);
      // ---- V^T B-frags from global (L2); issued early to hide latency ----
      bf16x8 vf[2][4];
      #pragma unroll
      for (int kh = 0; kh < 2; ++kh)
        #pragma unroll
        for (int dblk = 0; dblk < 4; ++dblk)
          vf[kh][dblk] = *(const bf16x8*)(vtq + (size_t)dblk * 16 * 4096 + kv0 + kh * 32);
      // lane (g,c15) holds P^T[kv = kv0 + n*16 + g*4 + r][q = qg0 + c15] (log2-scaled)
      // ---- causal mask (diagonal region only; wave-uniform branch) ----
      if (kv0 + 63 > qg0) {
        #pragma unroll
        for (int n = 0; n < 4; ++n)
          #pragma unroll
          for (int r = 0; r < 4; ++r)
            if (kv0 + n * 16 + g * 4 + r > qabs) s[n][r] = -1e30f;
      }
      // ---- online softmax (log2 domain; row q = c15) ----
      float pm = -1e30f;
      #pragma unroll
      for (int n = 0; n < 4; ++n)
        #pragma unroll
        for (int r = 0; r < 4; ++r) pm = fmaxf(pm, s[n][r]);
      pm = fmaxf(pm, __shfl_xor(pm, 16));
      pm = fmaxf(pm, __shfl_xor(pm, 32));
      if (!__all(pm <= m + 8.0f)) {   // defer-max THR=8 (log2 units; P <= 256)
        float nm = fmaxf(m, pm);
        float corr = exp2f(m - nm);
        m = nm; l *= corr;
        float cf[4];
        #pragma unroll
        for (int r = 0; r < 4; ++r) cf[r] = __shfl(corr, g * 4 + r);
        #pragma unroll
        for (int dblk = 0; dblk < 4; ++dblk)
          #pragma unroll
          for (int r = 0; r < 4; ++r) o[dblk][r] *= cf[r];
      }
      float rs = 0.0f;
      #pragma unroll
      for (int n = 0; n < 4; ++n)
        #pragma unroll
        for (int r = 0; r < 4; ++r) {
          float p = exp2f(s[n][r] - m);
          s[n][r] = p; rs += p;
        }
      rs += __shfl_xor(rs, 16);
      rs += __shfl_xor(rs, 32);
      l += rs;
      // ---- pack P^T pairs to bf16 words ----
      unsigned pk[4][2];
      #pragma unroll
      for (int n = 0; n < 4; ++n) {
        pk[n][0] = cvtpk(s[n][0], s[n][1]);
        pk[n][1] = cvtpk(s[n][2], s[n][3]);
      }
      // ---- redistribute to PV A-frags: pa[kh] = P[q=c15][kh*32 + g*8 + j] ----
      U8 pa[2];
      #pragma unroll
      for (int kh = 0; kh < 2; ++kh) {
        #pragma unroll
        for (int widx = 0; widx < 4; ++widx) {
          int src = (2 * (g & 1) + (widx >> 1)) * 16 + c15;
          unsigned lo = __shfl(pk[2 * kh][widx & 1], src);
          unsigned hi = __shfl(pk[2 * kh + 1][widx & 1], src);
          pa[kh].u[widx] = (g & 2) ? hi : lo;
        }
      }
      // ---- O += P * V ----
      __builtin_amdgcn_s_setprio(1);
      #pragma unroll
      for (int kh = 0; kh < 2; ++kh)
        #pragma unroll
        for (int dblk = 0; dblk < 4; ++dblk)
          o[dblk] = MFMA16(pa[kh].v, vf[kh][dblk], o[dblk]);
      __builtin_amdgcn_s_setprio(0);
    }
    __syncthreads();  // drains own-wave vmcnt (K DMA) + orders LDS for next tile
  }
  // ---- epilogue: normalize, store ctx ----
  float linv = 1.0f / l;
  float lf[4];
  #pragma unroll
  for (int r = 0; r < 4; ++r) lf[r] = __shfl(linv, g * 4 + r);
  #pragma unroll
  for (int dblk = 0; dblk < 4; ++dblk)
    #pragma unroll
    for (int r = 0; r < 4; ++r) {
      int q = qg0 + g * 4 + r;
      Ctx[((size_t)(b * S_ + q)) * D_ + h * DH_ + dblk * 16 + c15] = f2bf(o[dblk][r] * lf[r]);
    }
}

extern "C" void kernel_launch(void* const* d_in, const int* in_sizes, int n_in,
                              void* d_out, int out_size, void* d_ws, size_t ws_size,
                              hipStream_t stream) {
  (void)in_sizes; (void)n_in; (void)out_size; (void)ws_size;
  const float* x  = (const float*)d_in[0];
  const float* Wq = (const float*)d_in[1];
  const float* bq = (const float*)d_in[2];
  const float* Wk = (const float*)d_in[3];
  const float* bk = (const float*)d_in[4];
  const float* Wv = (const float*)d_in[5];
  const float* bv = (const float*)d_in[6];
  const float* Wo = (const float*)d_in[7];
  const float* bo = (const float*)d_in[8];
  float* out = (float*)d_out;
  char* ws = (char*)d_ws;

  const size_t MS = (size_t)B_ * S_;  // 4096
  short* xb  = (short*)(ws);                                  // 8 MB
  short* wqT = (short*)(ws + (size_t)8 * 1024 * 1024);        // 2 MB each, contiguous
  short* wkT = wqT + (size_t)D_ * D_;
  short* wvT = wkT + (size_t)D_ * D_;
  short* woT = wvT + (size_t)D_ * D_;
  short* qb  = (short*)(ws + (size_t)16 * 1024 * 1024);       // 8 MB each
  short* kb  = qb + MS * D_;
  short* vt  = kb + MS * D_;                                  // V^T [1024][4096]
  short* ctx = vt + MS * D_;
  float* cosT = (float*)(ws + (size_t)48 * 1024 * 1024);      // 256 KB each
  float* sinT = cosT + (size_t)S_ * 32;

  // 1. x -> bf16
  k_cvt<<<dim3((unsigned)(MS * D_ / 4 / 256)), 256, 0, stream>>>(x, xb, (int)(MS * D_ / 4));
  // 2. weights -> bf16 transposed (wqT/wkT contiguous => one [2048][1024] matrix)
  dim3 tb(32, 8);
  k_transpose<<<dim3(32, 32), tb, 0, stream>>>(Wq, wqT);
  k_transpose<<<dim3(32, 32), tb, 0, stream>>>(Wk, wkT);
  k_transpose<<<dim3(32, 32), tb, 0, stream>>>(Wv, wvT);
  k_transpose<<<dim3(32, 32), tb, 0, stream>>>(Wo, woT);
  // 3. rope table
  k_rope_table<<<dim3(S_ * 32 / 256), 256, 0, stream>>>(cosT, sinT);
  // 4a. fused Q,K projection + bias + RoPE (+ (1/8)*log2e fold into Q)
  k_gemm_qkv<<<dim3(16, 32), 256, 0, stream>>>(xb, wqT, bq, bk, cosT, sinT, qb, kb);
  // 4b. V^T projection (bias per row, bf16 out, coalesced)
  k_gemm_vt<<<dim3(32, 8), 256, 0, stream>>>(wvT, xb, bv, vt);
  // 5. causal flash attention (V read from vt global, no V LDS)
  k_flash<<<dim3((S_ / 64) * 32), 256, 0, stream>>>(qb, kb, vt, ctx);
  // 6. output projection (f32 out)
  k_gemm<<<dim3(8, 32), 256, 0, stream>>>(ctx, woT, bo, out, 4096, 1024, 1024);
}

// Round 7
// 138.484 us; speedup vs baseline: 1.2548x; 1.2548x over previous
//
#include <hip/hip_runtime.h>
#include <hip/hip_bf16.h>

#define B_  2
#define S_  2048
#define D_  1024
#define H_  16
#define DH_ 64

typedef __attribute__((ext_vector_type(8))) short bf16x8;
typedef __attribute__((ext_vector_type(4))) float f32x4;

__device__ __forceinline__ short f2bf(float f) {
  unsigned int u; __builtin_memcpy(&u, &f, 4);
  u = (u + 0x7FFFu + ((u >> 16) & 1u)) >> 16;
  return (short)u;
}
// packed f32x2 -> bf16x2 (RNE), lo = first arg
__device__ __forceinline__ unsigned cvtpk(float a, float b) {
  unsigned r;
  asm("v_cvt_pk_bf16_f32 %0, %1, %2" : "=v"(r) : "v"(a), "v"(b));
  return r;
}

#define GLOAD_LDS16(gp, lp) \
  __builtin_amdgcn_global_load_lds((const __attribute__((address_space(1))) void*)(gp), \
                                   (__attribute__((address_space(3))) void*)(lp), 16, 0, 0)

#define MFMA16(a, b, c) __builtin_amdgcn_mfma_f32_16x16x32_bf16(a, b, c, 0, 0, 0)

union U8 { unsigned u[4]; bf16x8 v; };

// ---------------- f32 -> bf16 convert (x) ----------------
__global__ __launch_bounds__(256) void k_cvt(const float* __restrict__ in,
                                             short* __restrict__ out, int n4) {
  int i = blockIdx.x * 256 + threadIdx.x;
  if (i >= n4) return;
  float4 v = ((const float4*)in)[i];
  short4 o; o.x = f2bf(v.x); o.y = f2bf(v.y); o.z = f2bf(v.z); o.w = f2bf(v.w);
  *(short4*)(out + (size_t)i * 4) = o;
}

// ---------------- 4 weights (f32 [K][N]) -> Wt (bf16 [N][K]), one launch ----------------
__global__ __launch_bounds__(256) void k_transpose4(const float* __restrict__ W0,
                                                    const float* __restrict__ W1,
                                                    const float* __restrict__ W2,
                                                    const float* __restrict__ W3,
                                                    short* __restrict__ WtBase) {
  __shared__ float tile[32][33];
  const float* W = (blockIdx.z == 0) ? W0 : (blockIdx.z == 1) ? W1 :
                   (blockIdx.z == 2) ? W2 : W3;
  short* Wt = WtBase + (size_t)blockIdx.z * D_ * D_;
  int tx = threadIdx.x, ty = threadIdx.y;
  int bx = blockIdx.x * 32, by = blockIdx.y * 32;
  #pragma unroll
  for (int i = 0; i < 32; i += 8)
    tile[ty + i][tx] = W[(size_t)(by + ty + i) * D_ + bx + tx];
  __syncthreads();
  #pragma unroll
  for (int i = 0; i < 32; i += 8)
    Wt[(size_t)(bx + ty + i) * D_ + by + tx] = f2bf(tile[tx][ty + i]);
}

// ---------------- RoPE cos/sin table ----------------
__global__ __launch_bounds__(256) void k_rope_table(float* __restrict__ cosT,
                                                    float* __restrict__ sinT) {
  int i = blockIdx.x * 256 + threadIdx.x;  // S_*32 entries
  int s = i >> 5, d = i & 31;
  float invf = exp2f(-(float)d * (13.287712379549449f / 32.0f)); // 10000^(-d/32)
  float ang = (float)s * invf;
  cosT[i] = cosf(ang);
  sinT[i] = sinf(ang);
}

// ---------------- fused QKV GEMM + bias + RoPE epilogue ----------------
// C[4096,3072] = xb * [wqT;wkT;wvT]^T; RoPE on q,k; Q scaled by (1/8)*log2e.
__global__ __launch_bounds__(256) void k_gemm_qkv(const short* __restrict__ A,
                                                  const short* __restrict__ Bt,
                                                  const float* __restrict__ bq,
                                                  const float* __restrict__ bk,
                                                  const float* __restrict__ bv,
                                                  const float* __restrict__ cosT,
                                                  const float* __restrict__ sinT,
                                                  short* __restrict__ qb,
                                                  short* __restrict__ kb,
                                                  short* __restrict__ vb) {
  const int K = 1024;
  __shared__ __align__(16) short lA[128 * 32];
  __shared__ __align__(16) short lB[128 * 32];
  const int tid = threadIdx.x;
  const int wid = tid >> 6, lane = tid & 63;
  const int brow = blockIdx.y * 128, bcol = blockIdx.x * 128;
  const int wr = wid >> 1, wc = wid & 1;
  const int g = lane >> 4, c15 = lane & 15;
  const int sr = lane >> 2, scol = (lane & 3) * 8;
  f32x4 acc[4][4] = {};

  for (int kt = 0; kt < K; kt += 32) {
    __syncthreads();
    #pragma unroll
    for (int ch = 0; ch < 2; ++ch) {
      const short* ga = A + (size_t)(brow + ch * 64 + wid * 16 + sr) * K + kt + scol;
      const short* gb = Bt + (size_t)(bcol + ch * 64 + wid * 16 + sr) * K + kt + scol;
      GLOAD_LDS16(ga, &lA[(ch * 64 + wid * 16) * 32]);
      GLOAD_LDS16(gb, &lB[(ch * 64 + wid * 16) * 32]);
    }
    __syncthreads();
    bf16x8 af[4], bfr[4];
    #pragma unroll
    for (int mi = 0; mi < 4; ++mi)
      af[mi] = *(const bf16x8*)&lA[(wr * 64 + mi * 16 + c15) * 32 + g * 8];
    #pragma unroll
    for (int ni = 0; ni < 4; ++ni)
      bfr[ni] = *(const bf16x8*)&lB[(wc * 64 + ni * 16 + c15) * 32 + g * 8];
    #pragma unroll
    for (int mi = 0; mi < 4; ++mi)
      #pragma unroll
      for (int ni = 0; ni < 4; ++ni)
        acc[mi][ni] = MFMA16(af[mi], bfr[ni], acc[mi][ni]);
  }

  // epilogue: segment select (block-uniform), bias, alpha, rope pair rotation
  const int seg = bcol >> 10;                       // 0=q 1=k 2=v
  const float* bp = (seg == 0) ? bq : (seg == 1) ? bk : bv;
  short* dst = (seg == 0) ? qb : (seg == 1) ? kb : vb;
  const float alpha = (seg == 0) ? 0.18033688f : 1.0f;  // (1/8)*log2(e)
  const bool rope = (seg < 2);
  #pragma unroll
  for (int mi = 0; mi < 4; ++mi) {
    #pragma unroll
    for (int ni = 0; ni < 2; ++ni) {
      int col  = bcol + wc * 64 + ni * 16 + c15;
      int lcol = col & 1023;
      int d    = col & 63;                          // 0..31 (ni<2)
      float b1 = bp[lcol], b2 = bp[lcol + 32];
      #pragma unroll
      for (int r = 0; r < 4; ++r) {
        int row = brow + wr * 64 + mi * 16 + g * 4 + r;
        float x1 = (acc[mi][ni][r]     + b1) * alpha;
        float x2 = (acc[mi][ni + 2][r] + b2) * alpha;
        float o1 = x1, o2 = x2;
        if (rope) {
          int s = row & (S_ - 1);
          float co = cosT[s * 32 + d], si = sinT[s * 32 + d];
          o1 = x1 * co - x2 * si;
          o2 = x1 * si + x2 * co;
        }
        dst[(size_t)row * 1024 + lcol]      = f2bf(o1);
        dst[(size_t)row * 1024 + lcol + 32] = f2bf(o2);
      }
    }
  }
}

// ---------------- bf16 GEMM (Wo): C = A*Bt^T + bias(col), f32 out ----------------
__global__ __launch_bounds__(256) void k_gemm(const short* __restrict__ A,
                                              const short* __restrict__ Bt,
                                              const float* __restrict__ bias,
                                              float* __restrict__ out,
                                              int M, int N, int K) {
  __shared__ __align__(16) short lA[128 * 32];
  __shared__ __align__(16) short lB[128 * 32];
  const int tid = threadIdx.x;
  const int wid = tid >> 6, lane = tid & 63;
  const int brow = blockIdx.y * 128, bcol = blockIdx.x * 128;
  const int wr = wid >> 1, wc = wid & 1;
  const int g = lane >> 4, c15 = lane & 15;
  const int sr = lane >> 2, scol = (lane & 3) * 8;
  f32x4 acc[4][4] = {};

  for (int kt = 0; kt < K; kt += 32) {
    __syncthreads();
    #pragma unroll
    for (int ch = 0; ch < 2; ++ch) {
      const short* ga = A + (size_t)(brow + ch * 64 + wid * 16 + sr) * K + kt + scol;
      const short* gb = Bt + (size_t)(bcol + ch * 64 + wid * 16 + sr) * K + kt + scol;
      GLOAD_LDS16(ga, &lA[(ch * 64 + wid * 16) * 32]);
      GLOAD_LDS16(gb, &lB[(ch * 64 + wid * 16) * 32]);
    }
    __syncthreads();
    bf16x8 af[4], bfr[4];
    #pragma unroll
    for (int mi = 0; mi < 4; ++mi)
      af[mi] = *(const bf16x8*)&lA[(wr * 64 + mi * 16 + c15) * 32 + g * 8];
    #pragma unroll
    for (int ni = 0; ni < 4; ++ni)
      bfr[ni] = *(const bf16x8*)&lB[(wc * 64 + ni * 16 + c15) * 32 + g * 8];
    #pragma unroll
    for (int mi = 0; mi < 4; ++mi)
      #pragma unroll
      for (int ni = 0; ni < 4; ++ni)
        acc[mi][ni] = MFMA16(af[mi], bfr[ni], acc[mi][ni]);
  }

  #pragma unroll
  for (int mi = 0; mi < 4; ++mi) {
    #pragma unroll
    for (int ni = 0; ni < 4; ++ni) {
      int col = bcol + wc * 64 + ni * 16 + c15;
      float bv = bias[col];
      #pragma unroll
      for (int r = 0; r < 4; ++r) {
        int row = brow + wr * 64 + mi * 16 + g * 4 + r;
        out[(size_t)row * N + col] = acc[mi][ni][r] + bv;
      }
    }
  }
}

// ---------------- causal flash attention with KV-split for long q-tiles ----------------
// R5-validated per-tile structure (swapped QK^T, K DMA-staged swizzled dbuf,
// V reg-staged transposed swizzled dbuf, in-reg softmax exp2-direct).
// Schedule (sched = bid>>5, 45 per bh):
//   sched<19  : whole block, qt = 18-sched (big first), tiles 0..qt -> ctx
//   sched>=19 : j=sched-19; qt = 31-(j>>1); half (j&1)==0 -> late tiles [h1..qt],
//               (j&1)==1 -> early tiles [0..h1-1]; partial (O,m,l) -> pO/pML, slot bh*26+j
__global__ __launch_bounds__(256) void k_flash(const short* __restrict__ Qb,
                                               const short* __restrict__ Kb,
                                               const short* __restrict__ Vb,
                                               short* __restrict__ Ctx,
                                               float* __restrict__ pO,
                                               float* __restrict__ pML) {
  __shared__ __align__(16) short Vt[2][64][72];  // V[kv][d] at Vt[d][kv^((d>>4)<<3)]
  __shared__ __align__(16) short Kl[2][4096];    // K[kv][d] at kv*64 + ((d>>3)^(kv&7))*8 + (d&7)
  const int bid = blockIdx.x;
  const int sched = bid >> 5, bh = bid & 31;
  int qt, t0, t1, sid = 0; bool split;
  if (sched < 19) { qt = 18 - sched; t0 = 0; t1 = qt; split = false; }
  else {
    int j = sched - 19; qt = 31 - (j >> 1);
    int h1 = (qt + 2) >> 1;                       // ceil((qt+1)/2)
    if ((j & 1) == 0) { t0 = h1; t1 = qt; }       // late half
    else              { t0 = 0;  t1 = h1 - 1; }   // early half
    split = true; sid = bh * 26 + j;
  }
  const int b   = bh >> 4, h = bh & 15;
  const int tid = threadIdx.x, w = tid >> 6, lane = tid & 63;
  const int g   = lane >> 4, c15 = lane & 15;
  const int qg0 = qt * 64 + w * 16;
  const int qabs = qg0 + c15;

  // Q fragments (B-operand of swapped QK^T): lane holds Q[q=c15][g*8+j (+32)]
  const short* qp = Qb + ((size_t)(b * S_ + qabs)) * D_ + h * DH_ + g * 8;
  bf16x8 qf0 = *(const bf16x8*)qp;
  bf16x8 qf1 = *(const bf16x8*)(qp + 32);

  // V staging: wave w stages d-slice [w*16, +16) for all 64 kv (lane = kv)
  const int vkv = lane;
  const int vd0 = w * 16;
  const int vcol = vkv ^ (w << 3);
  const short* vrow = Vb + (size_t)b * S_ * D_ + h * DH_ + vd0;

  // K staging (DMA): wave w covers idx = w*128 + it*64 + lane, 16B each
  const short* kbase = Kb + (size_t)b * S_ * D_ + h * DH_;
  const int kidx0 = w * 128 + lane;
  const int kkv0 = kidx0 >> 3, kdb0 = (kidx0 & 7) ^ (kkv0 & 7);
  const int kidx1 = kidx0 + 64;
  const int kkv1 = kidx1 >> 3, kdb1 = (kidx1 & 7) ^ (kkv1 & 7);

  f32x4 o[4] = {};
  float m = -1e30f, l = 0.0f;

  // prologue: stage K+V tile t0 into buf (t0&1)
  {
    const short* kb0 = kbase + (size_t)(t0 * 64) * D_;
    GLOAD_LDS16(kb0 + (size_t)kkv0 * D_ + kdb0 * 8, &Kl[t0 & 1][(w * 128) * 8]);
    GLOAD_LDS16(kb0 + (size_t)kkv1 * D_ + kdb1 * 8, &Kl[t0 & 1][(w * 128 + 64) * 8]);
    const short* vp = vrow + (size_t)(t0 * 64 + vkv) * D_;
    bf16x8 a = *(const bf16x8*)vp;
    bf16x8 c = *(const bf16x8*)(vp + 8);
    #pragma unroll
    for (int j = 0; j < 8; ++j) Vt[t0 & 1][vd0 + j][vcol] = a[j];
    #pragma unroll
    for (int j = 0; j < 8; ++j) Vt[t0 & 1][vd0 + 8 + j][vcol] = c[j];
  }
  __syncthreads();

  for (int t = t0; t <= t1; ++t) {
    const int kv0 = t * 64;
    // prefetch tile t+1: K via async DMA, V into regs (T14)
    bf16x8 nv0, nv1;
    if (t + 1 <= t1) {
      const short* kb2 = kbase + (size_t)(kv0 + 64) * D_;
      GLOAD_LDS16(kb2 + (size_t)kkv0 * D_ + kdb0 * 8, &Kl[(t + 1) & 1][(w * 128) * 8]);
      GLOAD_LDS16(kb2 + (size_t)kkv1 * D_ + kdb1 * 8, &Kl[(t + 1) & 1][(w * 128 + 64) * 8]);
      const short* vp = vrow + (size_t)(kv0 + 64 + vkv) * D_;
      nv0 = *(const bf16x8*)vp;
      nv1 = *(const bf16x8*)(vp + 8);
    }
    // ---- S^T = K * Q^T : A-frag = K rows from LDS (swizzled) ----
    const short* ks = &Kl[t & 1][0];
    f32x4 s[4] = {};
    __builtin_amdgcn_s_setprio(1);
    #pragma unroll
    for (int n = 0; n < 4; ++n) {
      int krow = (n * 16 + c15) * 64;
      bf16x8 k0 = *(const bf16x8*)&ks[krow + ((g ^ (c15 & 7)) * 8)];
      bf16x8 k1 = *(const bf16x8*)&ks[krow + (((g + 4) ^ (c15 & 7)) * 8)];
      s[n] = MFMA16(k0, qf0, s[n]);
      s[n] = MFMA16(k1, qf1, s[n]);
    }
    __builtin_amdgcn_s_setprio(0);
    // lane (g,c15) holds P^T[kv = kv0 + n*16 + g*4 + r][q = qg0 + c15] (log2-scaled)
    // ---- causal mask (diagonal tile only) ----
    if (kv0 + 63 > qg0) {
      #pragma unroll
      for (int n = 0; n < 4; ++n)
        #pragma unroll
        for (int r = 0; r < 4; ++r)
          if (kv0 + n * 16 + g * 4 + r > qabs) s[n][r] = -1e30f;
    }
    // ---- online softmax (log2 domain; row q = c15) ----
    float pm = -1e30f;
    #pragma unroll
    for (int n = 0; n < 4; ++n)
      #pragma unroll
      for (int r = 0; r < 4; ++r) pm = fmaxf(pm, s[n][r]);
    pm = fmaxf(pm, __shfl_xor(pm, 16));
    pm = fmaxf(pm, __shfl_xor(pm, 32));
    if (!__all(pm <= m + 8.0f)) {   // defer-max THR=8 (log2 units; P <= 256)
      float nm = fmaxf(m, pm);
      float corr = exp2f(m - nm);
      m = nm; l *= corr;
      float cf[4];
      #pragma unroll
      for (int r = 0; r < 4; ++r) cf[r] = __shfl(corr, g * 4 + r);
      #pragma unroll
      for (int dblk = 0; dblk < 4; ++dblk)
        #pragma unroll
        for (int r = 0; r < 4; ++r) o[dblk][r] *= cf[r];
    }
    float rs = 0.0f;
    #pragma unroll
    for (int n = 0; n < 4; ++n)
      #pragma unroll
      for (int r = 0; r < 4; ++r) {
        float p = exp2f(s[n][r] - m);
        s[n][r] = p; rs += p;
      }
    rs += __shfl_xor(rs, 16);
    rs += __shfl_xor(rs, 32);
    l += rs;
    // ---- pack P^T pairs to bf16 words ----
    unsigned pk[4][2];
    #pragma unroll
    for (int n = 0; n < 4; ++n) {
      pk[n][0] = cvtpk(s[n][0], s[n][1]);
      pk[n][1] = cvtpk(s[n][2], s[n][3]);
    }
    // ---- redistribute to PV A-frags: pa[kh] = P[q=c15][kh*32 + g*8 + j] ----
    U8 pa[2];
    #pragma unroll
    for (int kh = 0; kh < 2; ++kh) {
      #pragma unroll
      for (int widx = 0; widx < 4; ++widx) {
        int src = (2 * (g & 1) + (widx >> 1)) * 16 + c15;
        unsigned lo = __shfl(pk[2 * kh][widx & 1], src);
        unsigned hi = __shfl(pk[2 * kh + 1][widx & 1], src);
        pa[kh].u[widx] = (g & 2) ? hi : lo;
      }
    }
    // ---- O += P * V  (B-frag = b128 from transposed, swizzled Vt) ----
    __builtin_amdgcn_s_setprio(1);
    #pragma unroll
    for (int kh = 0; kh < 2; ++kh)
      #pragma unroll
      for (int dblk = 0; dblk < 4; ++dblk) {
        bf16x8 vbf = *(const bf16x8*)&Vt[t & 1][dblk * 16 + c15][kh * 32 + ((g ^ dblk) * 8)];
        o[dblk] = MFMA16(pa[kh].v, vbf, o[dblk]);
      }
    __builtin_amdgcn_s_setprio(0);
    // ---- write staged V tile t+1 ----
    if (t + 1 <= t1) {
      #pragma unroll
      for (int j = 0; j < 8; ++j) Vt[(t + 1) & 1][vd0 + j][vcol] = nv0[j];
      #pragma unroll
      for (int j = 0; j < 8; ++j) Vt[(t + 1) & 1][vd0 + 8 + j][vcol] = nv1[j];
    }
    __syncthreads();  // drains vmcnt (K DMA) + orders LDS for next tile
  }

  if (!split) {
    // ---- epilogue: normalize, store ctx ----
    float linv = 1.0f / l;
    float lf[4];
    #pragma unroll
    for (int r = 0; r < 4; ++r) lf[r] = __shfl(linv, g * 4 + r);
    #pragma unroll
    for (int dblk = 0; dblk < 4; ++dblk)
      #pragma unroll
      for (int r = 0; r < 4; ++r) {
        int q = qg0 + g * 4 + r;
        Ctx[((size_t)(b * S_ + q)) * D_ + h * DH_ + dblk * 16 + c15] = f2bf(o[dblk][r] * lf[r]);
      }
  } else {
    // ---- epilogue: raw partial O (f32) + per-row m,l ----
    float* po = pO + ((size_t)sid * 64 + w * 16) * 64;
    #pragma unroll
    for (int dblk = 0; dblk < 4; ++dblk)
      #pragma unroll
      for (int r = 0; r < 4; ++r)
        po[(g * 4 + r) * 64 + dblk * 16 + c15] = o[dblk][r];
    if (lane < 16) {   // lanes 0..15: g=0, c15=lane -> row w*16+lane
      pML[(size_t)sid * 128 + w * 16 + lane]      = m;
      pML[(size_t)sid * 128 + 64 + w * 16 + lane] = l;
    }
  }
}

// ---------------- combine split halves: ctx rows for qt in [19,31] ----------------
__global__ __launch_bounds__(256) void k_combine(const float* __restrict__ pO,
                                                 const float* __restrict__ pML,
                                                 short* __restrict__ Ctx) {
  const int p = blockIdx.x;           // 13 qt x 32 bh
  const int qt = 19 + (p >> 5), bh = p & 31;
  const int b = bh >> 4, h = bh & 15;
  const int jb = (31 - qt) * 2;
  const int sidB = bh * 26 + jb;      // late half
  const int sidA = bh * 26 + jb + 1;  // early half
  const int q = threadIdx.x >> 2;
  const int d0 = (threadIdx.x & 3) * 16;
  float mA = pML[(size_t)sidA * 128 + q], lA = pML[(size_t)sidA * 128 + 64 + q];
  float mB = pML[(size_t)sidB * 128 + q], lB = pML[(size_t)sidB * 128 + 64 + q];
  float M = fmaxf(mA, mB);
  float wA = exp2f(mA - M), wB = exp2f(mB - M);
  float inv = 1.0f / (lA * wA + lB * wB);
  const float* oA = pO + ((size_t)sidA * 64 + q) * 64 + d0;
  const float* oB = pO + ((size_t)sidB * 64 + q) * 64 + d0;
  short* cp = Ctx + ((size_t)(b * S_ + qt * 64 + q)) * D_ + h * DH_ + d0;
  #pragma unroll
  for (int i = 0; i < 16; i += 4) {
    float4 a = *(const float4*)(oA + i);
    float4 c = *(const float4*)(oB + i);
    cp[i + 0] = f2bf((a.x * wA + c.x * wB) * inv);
    cp[i + 1] = f2bf((a.y * wA + c.y * wB) * inv);
    cp[i + 2] = f2bf((a.z * wA + c.z * wB) * inv);
    cp[i + 3] = f2bf((a.w * wA + c.w * wB) * inv);
  }
}

extern "C" void kernel_launch(void* const* d_in, const int* in_sizes, int n_in,
                              void* d_out, int out_size, void* d_ws, size_t ws_size,
                              hipStream_t stream) {
  (void)in_sizes; (void)n_in; (void)out_size; (void)ws_size;
  const float* x  = (const float*)d_in[0];
  const float* Wq = (const float*)d_in[1];
  const float* bq = (const float*)d_in[2];
  const float* Wk = (const float*)d_in[3];
  const float* bk = (const float*)d_in[4];
  const float* Wv = (const float*)d_in[5];
  const float* bv = (const float*)d_in[6];
  const float* Wo = (const float*)d_in[7];
  const float* bo = (const float*)d_in[8];
  float* out = (float*)d_out;
  char* ws = (char*)d_ws;

  const size_t MS = (size_t)B_ * S_;  // 4096
  short* xb  = (short*)(ws);                                  // 8 MB (pre-flash)
  short* wqT = (short*)(ws + (size_t)8 * 1024 * 1024);        // 2 MB each, contiguous
  short* wkT = wqT + (size_t)D_ * D_;
  short* wvT = wkT + (size_t)D_ * D_;
  short* woT = wvT + (size_t)D_ * D_;                         // needed till the end
  short* qb  = (short*)(ws + (size_t)16 * 1024 * 1024);       // 8 MB each
  short* kb  = qb + MS * D_;
  short* vb  = kb + MS * D_;
  short* ctx = vb + MS * D_;
  float* cosT = (float*)(ws + (size_t)48 * 1024 * 1024);      // 256 KB each
  float* sinT = cosT + (size_t)S_ * 32;
  // flash partials (alias xb..wvT region, dead after qkv GEMM): 832 slots
  float* pO  = (float*)(ws);                                  // 13.6 MB < 14 MB
  float* pML = (float*)(ws + (size_t)48 * 1024 * 1024 + 512 * 1024);  // 426 KB

  // 1. x -> bf16
  k_cvt<<<dim3((unsigned)(MS * D_ / 4 / 256)), 256, 0, stream>>>(x, xb, (int)(MS * D_ / 4));
  // 2. weights -> bf16 transposed (one launch; wqT..woT contiguous)
  k_transpose4<<<dim3(32, 32, 4), dim3(32, 8), 0, stream>>>(Wq, Wk, Wv, Wo, wqT);
  // 3. rope table
  k_rope_table<<<dim3(S_ * 32 / 256), 256, 0, stream>>>(cosT, sinT);
  // 4. fused QKV projection + bias + RoPE (+ (1/8)*log2e fold into Q)
  k_gemm_qkv<<<dim3(24, 32), 256, 0, stream>>>(xb, wqT, bq, bk, bv, cosT, sinT, qb, kb, vb);
  // 5. causal flash attention, KV-split for qt>=19 (45 sched x 32 bh)
  k_flash<<<dim3(45 * 32), 256, 0, stream>>>(qb, kb, vb, ctx, pO, pML);
  // 6. combine split halves
  k_combine<<<dim3(13 * 32), 256, 0, stream>>>(pO, pML, ctx);
  // 7. output projection (f32 out)
  k_gemm<<<dim3(8, 32), 256, 0, stream>>>(ctx, woT, bo, out, 4096, 1024, 1024);
}